// Round 7
// baseline (439.747 us; speedup 1.0000x reference)
//
#include <hip/hip_runtime.h>
#include <hip/hip_bf16.h>
#include <cmath>
#include <cfloat>

#define BATCH 4
#define NPTS 8192
#define NPOINT 409
#define NBALLS (BATCH * NPOINT)   // 1636
#define REP_NS 20
#define REP_SEG 8                 // rep segments per query (one per wave)
#define SEG_LEN (NPTS / REP_SEG)  // 1024
#define REP_TASKS 512
#define NTASKS (REP_TASKS + NBALLS)   // 2148
#define NWORKERS 252
#define NBLOCKS (BATCH + NWORKERS)    // 256

#define UW 96                     // uni per-wave hit capacity (E[hits/1024pts]~1.1)
#define UH (8 * UW)               // 768

// ws layout (bytes):
//   [0, 6544)       : fps_idx  int[1636]  (memset 0xFF -> negative sentinel)
//   [6544, 6548)    : task counter       (memset 0xFF -> init -1; t = old+1)
//   [6548, 6552)    : done counter       (memset 0xFF -> init -1)
//   [8192, 12288)   : rep_part double[512]
//   [12288, 25376)  : uni_part double[1636]
// ONE memset covers [0, 6552).
// R7: batched publish — __syncthreads drains vmcnt(0), so a per-step
// agent-scope store made wave 0 eat the device-coherence store ack (~500+
// cyc) at EVERY barrier. Lane j of wave 0 latches far for slots ≡ j (mod 8);
// one predicated coalesced store per 8 steps. Unlock delay <=7 steps (~6us),
// absorbed by worker slack. R6's LDS atomicMax reverted (+13us regression:
// serialized RMW on the pre-barrier critical path) -> R5's 8-key tree.
#define WS_FPS_OFF 0
#define WS_CNT_OFF 6544
#define WS_DONE_OFF 6548
#define WS_REP_OFF 8192
#define WS_UNI_OFF 12288

typedef float v2f __attribute__((ext_vector_type(2)));

struct UniParams {
  float  thr[5];
  float  e[5];
  float  eden[5];
  int    ns[5];
};

template <int CTRL>
__device__ __forceinline__ unsigned dpp_max_u32(unsigned v) {
  const unsigned o = (unsigned)__builtin_amdgcn_update_dpp(
      0, (int)v, CTRL, 0xf, 0xf, true);
  return o > v ? o : v;
}

__device__ __forceinline__ unsigned long long umax64(unsigned long long a,
                                                     unsigned long long b) {
  return a > b ? a : b;
}

__device__ __forceinline__ void ins5(float v, float& t0, float& t1, float& t2,
                                     float& t3, float& t4) {
  if (v < t4) {
    t4 = v;
    if (t4 < t3) { float tmp = t3; t3 = t4; t4 = tmp; }
    if (t3 < t2) { float tmp = t2; t2 = t3; t3 = tmp; }
    if (t2 < t1) { float tmp = t1; t1 = t2; t2 = tmp; }
    if (t1 < t0) { float tmp = t0; t0 = t1; t1 = tmp; }
  }
}

__device__ __forceinline__ float rep_term(float d) {
  d = fmaxf(d, 0.0f);
  return 0.07f - sqrtf(d) * expf(-(d / 0.0009f));
}

// ---------------------------------------------------------------- fused kernel
// 256 blocks x 512 threads, 1 block/CU (145KB LDS) => ALL blocks co-resident
// by capacity; no dispatch-order assumption.
//   blocks [0,4)   : FPS; R7 publishes fps_idx in batches of 8 (see above).
//   blocks [4,256) : persistent workers pulling 2148 tasks off an atomic
//                    counter: tasks [0,512) = repulsion, [512,2148) = uniform.
//                    uni tasks poll fps_idx[ball] (0xFF sentinel).
//   all blocks     : arrive on done-counter (init -1 via 0xFF memset); the
//                    LAST block (old == NBLOCKS-2) does the final reduction.
__global__ __launch_bounds__(512, 2) void fused_kernel(const float* __restrict__ pcd,
                                                       int* __restrict__ fps_idx,
                                                       double* __restrict__ rep_part,
                                                       double* __restrict__ uni_part,
                                                       int* __restrict__ counter,
                                                       int* __restrict__ done,
                                                       float* __restrict__ out,
                                                       UniParams up, float rep_thr) {
  const int tid = threadIdx.x;
  const int lane = tid & 63;
  const int w = tid >> 6;
  extern __shared__ float smem[];   // 96 KB: X[8192] Y[8192] Z[8192] (fps only)

  // static shared (distinct storage per phase; no unions -> no cross-task races)
  __shared__ unsigned long long s_key[2][8];
  __shared__ float s_t5[REP_SEG][64][5];
  __shared__ float s_d0[REP_SEG][64];
  __shared__ int   s_cnt[REP_SEG][64];
  __shared__ float wx[8][UW], wy[8][UW], wz[8][UW], wd[8][UW];
  __shared__ int   s_wcnt[8];
  __shared__ float FX[UH], FY[UH], FZ[UH], FD[UH];
  __shared__ float CX[5][131], CY[5][131], CZ[5][131];
  __shared__ double dpart[8], rpart[8];
  __shared__ int s_task, s_qidx, s_last;

  if (blockIdx.x < BATCH) {
    // ---------------- FPS ----------------
    const int b = blockIdx.x;
    const float* P = pcd + b * NPTS * 3;
    float* X = smem;
    float* Y = smem + NPTS;
    float* Z = smem + 2 * NPTS;

    for (int i = tid; i < NPTS; i += 512) {
      X[i] = P[i * 3 + 0];
      Y[i] = P[i * 3 + 1];
      Z[i] = P[i * 3 + 2];
    }

    v2f px[8], py[8], pz[8], dist[8];
    const int base = tid * 16;
#pragma unroll
    for (int k = 0; k < 8; k++) {
      const int i0 = (base + 2 * k) * 3;
      const int i1 = (base + 2 * k + 1) * 3;
      px[k] = (v2f){P[i0 + 0], P[i1 + 0]};
      py[k] = (v2f){P[i0 + 1], P[i1 + 1]};
      pz[k] = (v2f){P[i0 + 2], P[i1 + 2]};
      dist[k] = (v2f){1e10f, 1e10f};
    }
#pragma unroll
    for (int k = 0; k < 8; k++) {
      asm volatile("" : "+v"(px[k]), "+v"(py[k]), "+v"(pz[k]));
    }

    __syncthreads();

    int myfar = 0;                  // lane j holds far for slots ≡ j (mod 8);
                                    // lane 0 starts with slot 0's pick (= 0)
    float fx = X[0], fy = Y[0], fz = Z[0];
    for (int s = 0; s < NPOINT - 1; s++) {     // 408 reduces (slots 1..408)
      const v2f fxv = (v2f){fx, fx};
      const v2f fyv = (v2f){fy, fy};
      const v2f fzv = (v2f){fz, fz};
#pragma unroll
      for (int k = 0; k < 8; k++) {
#pragma clang fp contract(off)
        const v2f dx = px[k] - fxv;
        const v2f dy = py[k] - fyv;
        const v2f dz = pz[k] - fzv;
        const v2f d  = (dx * dx + dy * dy) + dz * dz;
        dist[k].x = fminf(dist[k].x, d.x);
        dist[k].y = fminf(dist[k].y, d.y);
      }

      // thread-local max, 3-ary grouping -> v_max3_f32 fusion (8 inst vs 15).
      // max over finite floats is association-free -> bit-identical result.
      const float a0 = fmaxf(fmaxf(dist[0].x, dist[0].y), dist[1].x);
      const float a1 = fmaxf(fmaxf(dist[1].y, dist[2].x), dist[2].y);
      const float a2 = fmaxf(fmaxf(dist[3].x, dist[3].y), dist[4].x);
      const float a3 = fmaxf(fmaxf(dist[4].y, dist[5].x), dist[5].y);
      const float a4 = fmaxf(fmaxf(dist[6].x, dist[6].y), dist[7].x);
      const float b0 = fmaxf(fmaxf(a0, a1), a2);
      const float b1 = fmaxf(fmaxf(a3, a4), dist[7].y);
      const float tmax = fmaxf(b0, b1);

      // dist >= 0 -> IEEE f32 bits are order-isomorphic -> u32 DPP max
      const unsigned tb = __float_as_uint(tmax);
      unsigned rb = tb;
      rb = dpp_max_u32<0x111>(rb);   // row_shr:1
      rb = dpp_max_u32<0x112>(rb);   // row_shr:2
      rb = dpp_max_u32<0x114>(rb);   // row_shr:4
      rb = dpp_max_u32<0x118>(rb);   // row_shr:8
      rb = dpp_max_u32<0x142>(rb);   // row_bcast:15
      rb = dpp_max_u32<0x143>(rb);   // row_bcast:31
      const unsigned wb = (unsigned)__builtin_amdgcn_readlane((int)rb, 63);

      const unsigned long long hit = __ballot(tb == wb);
      const int par = s & 1;
      if (tb == wb && (hit & ((1ull << lane) - 1ull)) == 0ull) {
        // first (lowest-lane) holder of the wave max: find smallest local idx
        const float wv = __uint_as_float(wb);
        int li = 0;
#pragma unroll
        for (int j = 15; j >= 0; j--) {
          const float v = (j & 1) ? dist[j >> 1].y : dist[j >> 1].x;
          li = (v == wv) ? j : li;       // descending overwrite -> smallest j
        }
        const unsigned bidx = (unsigned)(base + li);
        s_key[par][w] = ((unsigned long long)wb << 32) |
                        (unsigned long long)(0xFFFFFFFFu - bidx);
      }
      __syncthreads();

      // depth-3 max tree (keys unique: idx distinct -> order-independent)
      const unsigned long long k0 = s_key[par][0], k1 = s_key[par][1];
      const unsigned long long k2 = s_key[par][2], k3 = s_key[par][3];
      const unsigned long long k4 = s_key[par][4], k5 = s_key[par][5];
      const unsigned long long k6 = s_key[par][6], k7 = s_key[par][7];
      const unsigned long long kbk =
          umax64(umax64(umax64(k0, k1), umax64(k2, k3)),
                 umax64(umax64(k4, k5), umax64(k6, k7)));
      const int far = (int)(0xFFFFFFFFu - (unsigned)(kbk & 0xFFFFFFFFull));

      // batched publish: latch far for slot s+1; store 8 slots per 8 steps
      const int sl = s + 1;
      if ((sl & 7) == lane) myfar = far;          // lanes 0..7 only can match
      if ((sl & 7) == 7 && w == 0 && lane < 8) {
        __hip_atomic_store(&fps_idx[b * NPOINT + (sl - 7) + lane], myfar,
                           __ATOMIC_RELAXED, __HIP_MEMORY_SCOPE_AGENT);
      }

      fx = X[far];                   // wave-uniform LDS broadcast (conflict-free)
      fy = Y[far];
      fz = Z[far];
    }
    // final slot 408 (408&7 == 0 -> held by lane 0)
    if (w == 0 && lane == 0) {
      __hip_atomic_store(&fps_idx[b * NPOINT + NPOINT - 1], myfar,
                         __ATOMIC_RELAXED, __HIP_MEMORY_SCOPE_AGENT);
    }
  } else {
    // ---------------- persistent workers (dynamic stealing) ----------------
    const double wj_tab[5] = {0.16 / (5.0 * 1636.0 * 32.0),
                              0.64 / (5.0 * 1636.0 * 65.0),
                              1.0  / (5.0 * 1636.0 * 81.0),
                              1.44 / (5.0 * 1636.0 * 98.0),
                              2.56 / (5.0 * 1636.0 * 131.0)};

    while (true) {
      __syncthreads();               // protects s_task + task-shared reuse
      if (tid == 0) s_task = atomicAdd(counter, 1) + 1;   // counter init -1
      __syncthreads();
      const int t = s_task;
      if (t >= NTASKS) break;        // uniform exit -> arrival

      if (t < REP_TASKS) {
        // ---------------- repulsion task (512 thr) ----------------
        const int b = t >> 7;                       // 128 tasks per batch
        const int q = ((t & 127) << 6) + lane;
        const float* P = pcd + b * NPTS * 3;

        const float qx = P[q * 3 + 0], qy = P[q * 3 + 1], qz = P[q * 3 + 2];

        int cnt = 0;
        float d0 = 0.0f;
        float t0 = FLT_MAX, t1 = FLT_MAX, t2 = FLT_MAX, t3 = FLT_MAX, t4 = FLT_MAX;

        const int wu = __builtin_amdgcn_readfirstlane(w);
        const float* S = P + wu * SEG_LEN * 3;
#pragma unroll 4
        for (int i = 0; i < SEG_LEN; i++) {
          const float x = S[i * 3 + 0];             // uniform addr -> scalar loads
          const float y = S[i * 3 + 1];
          const float z = S[i * 3 + 2];
          const float dx = qx - x, dy = qy - y, dz = qz - z;
          const float d = dx * dx + dy * dy + dz * dz;
          if (d <= rep_thr && cnt < REP_NS) {
            if (cnt == 0) d0 = d;
            ins5(d, t0, t1, t2, t3, t4);
            cnt++;
          }
        }

        s_t5[w][lane][0] = t0; s_t5[w][lane][1] = t1; s_t5[w][lane][2] = t2;
        s_t5[w][lane][3] = t3; s_t5[w][lane][4] = t4;
        s_d0[w][lane] = d0;
        s_cnt[w][lane] = cnt;
        __syncthreads();

        if (w == 0) {
          int total = 0;
          float fd0 = 0.0f;
          int first_seen = 0;
          float n0 = FLT_MAX, n1 = FLT_MAX, n2 = FLT_MAX, n3 = FLT_MAX, n4 = FLT_MAX;
#pragma unroll
          for (int sg = 0; sg < REP_SEG; sg++) {
            const int c = s_cnt[sg][lane];
            if (c > 0 && !first_seen) { fd0 = s_d0[sg][lane]; first_seen = 1; }
            total += c;
#pragma unroll
            for (int j = 0; j < 5; j++) ins5(s_t5[sg][lane][j], n0, n1, n2, n3, n4);
          }

          if (total > REP_NS) {
            // cap binds across segments (astronomically rare): exact rescan
            int c2 = 0;
            n0 = FLT_MAX; n1 = FLT_MAX; n2 = FLT_MAX; n3 = FLT_MAX; n4 = FLT_MAX;
            for (int i = 0; i < NPTS && c2 < REP_NS; i++) {
              const float dx = qx - P[i * 3 + 0];
              const float dy = qy - P[i * 3 + 1];
              const float dz = qz - P[i * 3 + 2];
              const float d = dx * dx + dy * dy + dz * dz;
              if (d <= rep_thr) { ins5(d, n0, n1, n2, n3, n4); c2++; }
            }
          } else {
            for (int c = total; c < REP_NS; c++) ins5(fd0, n0, n1, n2, n3, n4);
          }

          float sum = rep_term(n1) + rep_term(n2) + rep_term(n3) + rep_term(n4);
#pragma unroll
          for (int off = 32; off >= 1; off >>= 1) sum += __shfl_down(sum, off);
          if (lane == 0) rep_part[t] = (double)sum;
        }
      } else {
        // ---------------- uniform task (8 waves) --------
        const int ball = t - REP_TASKS;
        const int b = ball / NPOINT;
        const float* P = pcd + b * NPTS * 3;

        if (tid == 0) {
          int v = __hip_atomic_load(&fps_idx[ball], __ATOMIC_RELAXED,
                                    __HIP_MEMORY_SCOPE_AGENT);
          while (v < 0) {
            __builtin_amdgcn_s_sleep(32);
            v = __hip_atomic_load(&fps_idx[ball], __ATOMIC_RELAXED,
                                  __HIP_MEMORY_SCOPE_AGENT);
          }
          s_qidx = v;
        }
        __syncthreads();
        const int qidx = s_qidx;
        const float qx = P[qidx * 3 + 0], qy = P[qidx * 3 + 1], qz = P[qidx * 3 + 2];

        // scan this wave's contiguous 1024-point segment (index order kept)
        int wcnt = 0;
        const float* S = P + w * 1024 * 3;
        for (int it = 0; it < 16; it++) {
          const int j = it * 64 + lane;
          const float x = S[j * 3 + 0];
          const float y = S[j * 3 + 1];
          const float z = S[j * 3 + 2];
          const float dx = qx - x, dy = qy - y, dz = qz - z;
          const float d = dx * dx + dy * dy + dz * dz;
          const bool hitp = (d <= up.thr[4]);
          const unsigned long long m = __ballot(hitp);
          if (hitp) {
            const int pos = wcnt + __popcll(m & ((1ull << lane) - 1ull));
            if (pos < UW) {
              wx[w][pos] = x; wy[w][pos] = y; wz[w][pos] = z; wd[w][pos] = d;
            }
          }
          wcnt += __popcll(m);
        }
        if (lane == 0) s_wcnt[w] = min(wcnt, UW);
        __syncthreads();

        int off = 0;
#pragma unroll
        for (int w2 = 0; w2 < 8; w2++) {
          if (w2 == w) break;
          off += s_wcnt[w2];
        }
        for (int i = lane; i < s_wcnt[w]; i += 64) {
          FX[off + i] = wx[w][i]; FY[off + i] = wy[w][i];
          FZ[off + i] = wz[w][i]; FD[off + i] = wd[w][i];
        }
        __syncthreads();
        int c = 0;
#pragma unroll
        for (int w2 = 0; w2 < 8; w2++) c += s_wcnt[w2];   // >=1 (self hit)

        double local = 0.0;
        if (w < 5) {
          const int jp = w;
          const float thr = up.thr[jp];
          const int nsj = up.ns[jp];

          int cnt2 = 0;
          for (int bse = 0; bse < c; bse += 64) {
            const int e = bse + lane;
            const bool pred = (e < c) && (FD[e] <= thr);
            const unsigned long long m = __ballot(pred);
            if (pred) {
              const int pos = cnt2 + __popcll(m & ((1ull << lane) - 1ull));
              if (pos < nsj) {
                CX[jp][pos] = FX[e]; CY[jp][pos] = FY[e]; CZ[jp][pos] = FZ[e];
              }
            }
            cnt2 += __popcll(m);
          }
          const int cj = min(cnt2, nsj);     // >= 1 (self hit)
          const int pads = nsj - cj;
          const int istart = (pads > 0) ? 1 : 0;

          if (pads > 0 && lane == 0) {
            // pad rows + row 0: second-smallest = 0 exactly
            const float ud = sqrtf(fabsf(1e-8f));
            const float dd = ud - up.e[jp];
            const float tt = (dd * dd) / up.eden[jp];
            local += (double)tt * wj_tab[jp] * (double)(pads + 1);
          }

          for (int r = istart + lane; r < cj; r += 64) {
            const float xi = CX[jp][r], yi = CY[jp][r], zi = CZ[jp][r];
            float mm = FLT_MAX;
            for (int e2 = 0; e2 < cj; e2++) {
              if (e2 == r) continue;
              const float dx = xi - CX[jp][e2];
              const float dy = yi - CY[jp][e2];
              const float dz = zi - CZ[jp][e2];
              const float d = dx * dx + dy * dy + dz * dz;
              if (d < mm) mm = d;
            }
            const float ud = sqrtf(fabsf(mm + 1e-8f));
            const float dd = ud - up.e[jp];
            const float tt = (dd * dd) / up.eden[jp];
            local += (double)tt * wj_tab[jp];
          }
        }

#pragma unroll
        for (int o = 32; o >= 1; o >>= 1) local += __shfl_down(local, o);
        if (lane == 0) dpart[w] = local;
        __syncthreads();
        if (tid == 0) {
          double u = 0.0;
#pragma unroll
          for (int w2 = 0; w2 < 8; w2++) u += dpart[w2];
          uni_part[ball] = u;
        }
      }
    }
  }

  // ---------------- arrival + last-block finalize ----------------
  __syncthreads();                   // all block stores issued & drained
  if (tid == 0) {
    __threadfence();                 // release: publish this block's partials
    const int old = __hip_atomic_fetch_add(done, 1, __ATOMIC_ACQ_REL,
                                           __HIP_MEMORY_SCOPE_AGENT);
    s_last = (old == NBLOCKS - 2) ? 1 : 0;   // init -1 -> last sees 254
    if (s_last) __threadfence();     // acquire: see everyone's partials
  }
  __syncthreads();
  if (s_last) {
    double u = 0.0, r = 0.0;
    for (int i = tid; i < NBALLS; i += 512) u += uni_part[i];
    for (int i = tid; i < REP_TASKS; i += 512) r += rep_part[i];
#pragma unroll
    for (int o = 32; o >= 1; o >>= 1) {
      u += __shfl_down(u, o);
      r += __shfl_down(r, o);
    }
    if (lane == 0) { dpart[w] = u; rpart[w] = r; }
    __syncthreads();
    if (tid == 0) {
      double us = 0.0, rs = 0.0;
#pragma unroll
      for (int w2 = 0; w2 < 8; w2++) { us += dpart[w2]; rs += rpart[w2]; }
      out[0] = (float)us;
      out[1] = (float)(rs * (1.0 / 131072.0));
    }
  }
}

// ---------------------------------------------------------------- launch
extern "C" void kernel_launch(void* const* d_in, const int* in_sizes, int n_in,
                              void* d_out, int out_size, void* d_ws, size_t ws_size,
                              hipStream_t stream) {
  (void)in_sizes; (void)n_in; (void)out_size; (void)ws_size;
  const float* pcd = (const float*)d_in[0];
  float* out = (float*)d_out;
  int*    fps      = (int*)((char*)d_ws + WS_FPS_OFF);
  int*    counter  = (int*)((char*)d_ws + WS_CNT_OFF);
  int*    done     = (int*)((char*)d_ws + WS_DONE_OFF);
  double* rep_part = (double*)((char*)d_ws + WS_REP_OFF);
  double* uni_part = (double*)((char*)d_ws + WS_UNI_OFF);

  const float rep_thr = (float)(0.07 * 0.07);

  UniParams up;
  const double ps[5] = {0.004, 0.008, 0.01, 0.012, 0.016};
  for (int j = 0; j < 5; j++) {
    const int ns = (int)(8192.0 * ps[j]);            // 32, 65, 81, 98, 131
    const double r = sqrt(ps[j]);
    up.thr[j] = (float)(r * r);
    const double disk = M_PI * ps[j] / (double)ns;
    const double el = sqrt(2.0 * disk / 1.732);
    up.e[j] = (float)el;
    up.eden[j] = (float)(el + 1e-8);
    up.ns[j] = ns;
  }

  // ONE memset: fps_idx sentinels (0xFF -> negative), task counter -> -1,
  // done counter -> -1.
  hipMemsetAsync(fps, 0xFF, WS_DONE_OFF + sizeof(int), stream);

  static const int kDynLds = NPTS * 3 * (int)sizeof(float);   // 98304
  (void)hipFuncSetAttribute((const void*)fused_kernel,
                            hipFuncAttributeMaxDynamicSharedMemorySize, kDynLds);

  fused_kernel<<<NBLOCKS, 512, kDynLds, stream>>>(pcd, fps, rep_part, uni_part,
                                                  counter, done, out, up, rep_thr);
}

// Round 8
// 405.399 us; speedup vs baseline: 1.0847x; 1.0847x over previous
//
#include <hip/hip_runtime.h>
#include <hip/hip_bf16.h>
#include <cmath>
#include <cfloat>

#define BATCH 4
#define NPTS 8192
#define NPOINT 409
#define NBALLS (BATCH * NPOINT)   // 1636
#define REP_NS 20
#define REP_SEG 8                 // rep segments per query (one per wave)
#define SEG_LEN (NPTS / REP_SEG)  // 1024
#define REP_TASKS 512
#define NTASKS (REP_TASKS + NBALLS)   // 2148
#define NWORKERS 252
#define NBLOCKS (BATCH + NWORKERS)    // 256

#define UW 96                     // uni per-wave hit capacity (E[hits/1024pts]~1.1)
#define UH (8 * UW)               // 768

// ws layout (bytes):
//   [0, 6544)       : fps_idx  int[1636]  (memset 0xFF -> negative sentinel)
//   [6544, 6548)    : task counter       (memset 0xFF -> init -1; t = old+1)
//   [6548, 6552)    : done counter       (memset 0xFF -> init -1)
//   [8192, 12288)   : rep_part double[512]
//   [12288, 25376)  : uni_part double[1636]
// ONE memset covers [0, 6552).
// R8 = R5 structure (proven 371us kernel; R6 atomic and R7 batched-publish
// both regressed and are reverted) + FP contraction in the FPS dist update:
// sub,mul,fma,fma (6 ops/pt) vs contract(off)'s 8 — cuts the dominant
// issue-bound phase ~25%. Picks flip only on <=1-ulp near-ties of the top-2
// of 8192 dists (negligible); published indices otherwise bit-identical.
#define WS_FPS_OFF 0
#define WS_CNT_OFF 6544
#define WS_DONE_OFF 6548
#define WS_REP_OFF 8192
#define WS_UNI_OFF 12288

typedef float v2f __attribute__((ext_vector_type(2)));

struct UniParams {
  float  thr[5];
  float  e[5];
  float  eden[5];
  int    ns[5];
};

template <int CTRL>
__device__ __forceinline__ unsigned dpp_max_u32(unsigned v) {
  const unsigned o = (unsigned)__builtin_amdgcn_update_dpp(
      0, (int)v, CTRL, 0xf, 0xf, true);
  return o > v ? o : v;
}

__device__ __forceinline__ unsigned long long umax64(unsigned long long a,
                                                     unsigned long long b) {
  return a > b ? a : b;
}

__device__ __forceinline__ void ins5(float v, float& t0, float& t1, float& t2,
                                     float& t3, float& t4) {
  if (v < t4) {
    t4 = v;
    if (t4 < t3) { float tmp = t3; t3 = t4; t4 = tmp; }
    if (t3 < t2) { float tmp = t2; t2 = t3; t3 = tmp; }
    if (t2 < t1) { float tmp = t1; t1 = t2; t2 = tmp; }
    if (t1 < t0) { float tmp = t0; t0 = t1; t1 = tmp; }
  }
}

__device__ __forceinline__ float rep_term(float d) {
  d = fmaxf(d, 0.0f);
  return 0.07f - sqrtf(d) * expf(-(d / 0.0009f));
}

// ---------------------------------------------------------------- fused kernel
// 256 blocks x 512 threads, 1 block/CU (145KB LDS) => ALL blocks co-resident
// by capacity; no dispatch-order assumption.
//   blocks [0,4)   : FPS; publishes fps_idx at loop top (store ack hides under
//                    the following dist phase — R7 proved this was already
//                    off the critical path).
//   blocks [4,256) : persistent workers pulling 2148 tasks off an atomic
//                    counter: tasks [0,512) = repulsion, [512,2148) = uniform.
//                    uni tasks poll fps_idx[ball] (0xFF sentinel).
//   all blocks     : arrive on done-counter (init -1 via 0xFF memset); the
//                    LAST block (old == NBLOCKS-2) does the final reduction.
__global__ __launch_bounds__(512, 2) void fused_kernel(const float* __restrict__ pcd,
                                                       int* __restrict__ fps_idx,
                                                       double* __restrict__ rep_part,
                                                       double* __restrict__ uni_part,
                                                       int* __restrict__ counter,
                                                       int* __restrict__ done,
                                                       float* __restrict__ out,
                                                       UniParams up, float rep_thr) {
  const int tid = threadIdx.x;
  const int lane = tid & 63;
  const int w = tid >> 6;
  extern __shared__ float smem[];   // 96 KB: X[8192] Y[8192] Z[8192] (fps only)

  // static shared (distinct storage per phase; no unions -> no cross-task races)
  __shared__ unsigned long long s_key[2][8];
  __shared__ float s_t5[REP_SEG][64][5];
  __shared__ float s_d0[REP_SEG][64];
  __shared__ int   s_cnt[REP_SEG][64];
  __shared__ float wx[8][UW], wy[8][UW], wz[8][UW], wd[8][UW];
  __shared__ int   s_wcnt[8];
  __shared__ float FX[UH], FY[UH], FZ[UH], FD[UH];
  __shared__ float CX[5][131], CY[5][131], CZ[5][131];
  __shared__ double dpart[8], rpart[8];
  __shared__ int s_task, s_qidx, s_last;

  if (blockIdx.x < BATCH) {
    // ---------------- FPS ----------------
    const int b = blockIdx.x;
    const float* P = pcd + b * NPTS * 3;
    float* X = smem;
    float* Y = smem + NPTS;
    float* Z = smem + 2 * NPTS;

    for (int i = tid; i < NPTS; i += 512) {
      X[i] = P[i * 3 + 0];
      Y[i] = P[i * 3 + 1];
      Z[i] = P[i * 3 + 2];
    }

    v2f px[8], py[8], pz[8], dist[8];
    const int base = tid * 16;
#pragma unroll
    for (int k = 0; k < 8; k++) {
      const int i0 = (base + 2 * k) * 3;
      const int i1 = (base + 2 * k + 1) * 3;
      px[k] = (v2f){P[i0 + 0], P[i1 + 0]};
      py[k] = (v2f){P[i0 + 1], P[i1 + 1]};
      pz[k] = (v2f){P[i0 + 2], P[i1 + 2]};
      dist[k] = (v2f){1e10f, 1e10f};
    }
#pragma unroll
    for (int k = 0; k < 8; k++) {
      asm volatile("" : "+v"(px[k]), "+v"(py[k]), "+v"(pz[k]));
    }

    __syncthreads();

    int far = 0;
    float fx = X[0], fy = Y[0], fz = Z[0];
    for (int s = 0; s < NPOINT; s++) {
      if (tid == 0) {
        __hip_atomic_store(&fps_idx[b * NPOINT + s], far,
                           __ATOMIC_RELAXED, __HIP_MEMORY_SCOPE_AGENT);
      }

      const v2f fxv = (v2f){fx, fx};
      const v2f fyv = (v2f){fy, fy};
      const v2f fzv = (v2f){fz, fz};
#pragma unroll
      for (int k = 0; k < 8; k++) {
#pragma clang fp contract(fast)
        const v2f dx = px[k] - fxv;
        const v2f dy = py[k] - fyv;
        const v2f dz = pz[k] - fzv;
        const v2f d  = (dx * dx + dy * dy) + dz * dz;
        dist[k].x = fminf(dist[k].x, d.x);
        dist[k].y = fminf(dist[k].y, d.y);
      }

      // thread-local max, 3-ary grouping -> v_max3_f32 fusion (8 inst vs 15).
      // max over finite floats is association-free -> bit-identical result.
      const float a0 = fmaxf(fmaxf(dist[0].x, dist[0].y), dist[1].x);
      const float a1 = fmaxf(fmaxf(dist[1].y, dist[2].x), dist[2].y);
      const float a2 = fmaxf(fmaxf(dist[3].x, dist[3].y), dist[4].x);
      const float a3 = fmaxf(fmaxf(dist[4].y, dist[5].x), dist[5].y);
      const float a4 = fmaxf(fmaxf(dist[6].x, dist[6].y), dist[7].x);
      const float b0 = fmaxf(fmaxf(a0, a1), a2);
      const float b1 = fmaxf(fmaxf(a3, a4), dist[7].y);
      const float tmax = fmaxf(b0, b1);

      // dist >= 0 -> IEEE f32 bits are order-isomorphic -> u32 DPP max
      const unsigned tb = __float_as_uint(tmax);
      unsigned rb = tb;
      rb = dpp_max_u32<0x111>(rb);   // row_shr:1
      rb = dpp_max_u32<0x112>(rb);   // row_shr:2
      rb = dpp_max_u32<0x114>(rb);   // row_shr:4
      rb = dpp_max_u32<0x118>(rb);   // row_shr:8
      rb = dpp_max_u32<0x142>(rb);   // row_bcast:15
      rb = dpp_max_u32<0x143>(rb);   // row_bcast:31
      const unsigned wb = (unsigned)__builtin_amdgcn_readlane((int)rb, 63);

      const unsigned long long hit = __ballot(tb == wb);
      const int par = s & 1;
      if (tb == wb && (hit & ((1ull << lane) - 1ull)) == 0ull) {
        // first (lowest-lane) holder of the wave max: find smallest local idx
        const float wv = __uint_as_float(wb);
        int li = 0;
#pragma unroll
        for (int j = 15; j >= 0; j--) {
          const float v = (j & 1) ? dist[j >> 1].y : dist[j >> 1].x;
          li = (v == wv) ? j : li;       // descending overwrite -> smallest j
        }
        const unsigned bidx = (unsigned)(base + li);
        s_key[par][w] = ((unsigned long long)wb << 32) |
                        (unsigned long long)(0xFFFFFFFFu - bidx);
      }
      __syncthreads();

      // depth-3 max tree (keys unique: idx distinct -> order-independent)
      const unsigned long long k0 = s_key[par][0], k1 = s_key[par][1];
      const unsigned long long k2 = s_key[par][2], k3 = s_key[par][3];
      const unsigned long long k4 = s_key[par][4], k5 = s_key[par][5];
      const unsigned long long k6 = s_key[par][6], k7 = s_key[par][7];
      const unsigned long long kbk =
          umax64(umax64(umax64(k0, k1), umax64(k2, k3)),
                 umax64(umax64(k4, k5), umax64(k6, k7)));
      far = (int)(0xFFFFFFFFu - (unsigned)(kbk & 0xFFFFFFFFull));
      fx = X[far];                   // wave-uniform LDS broadcast (conflict-free)
      fy = Y[far];
      fz = Z[far];
    }
  } else {
    // ---------------- persistent workers (dynamic stealing) ----------------
    const double wj_tab[5] = {0.16 / (5.0 * 1636.0 * 32.0),
                              0.64 / (5.0 * 1636.0 * 65.0),
                              1.0  / (5.0 * 1636.0 * 81.0),
                              1.44 / (5.0 * 1636.0 * 98.0),
                              2.56 / (5.0 * 1636.0 * 131.0)};

    while (true) {
      __syncthreads();               // protects s_task + task-shared reuse
      if (tid == 0) s_task = atomicAdd(counter, 1) + 1;   // counter init -1
      __syncthreads();
      const int t = s_task;
      if (t >= NTASKS) break;        // uniform exit -> arrival

      if (t < REP_TASKS) {
        // ---------------- repulsion task (512 thr) ----------------
        const int b = t >> 7;                       // 128 tasks per batch
        const int q = ((t & 127) << 6) + lane;
        const float* P = pcd + b * NPTS * 3;

        const float qx = P[q * 3 + 0], qy = P[q * 3 + 1], qz = P[q * 3 + 2];

        int cnt = 0;
        float d0 = 0.0f;
        float t0 = FLT_MAX, t1 = FLT_MAX, t2 = FLT_MAX, t3 = FLT_MAX, t4 = FLT_MAX;

        const int wu = __builtin_amdgcn_readfirstlane(w);
        const float* S = P + wu * SEG_LEN * 3;
#pragma unroll 4
        for (int i = 0; i < SEG_LEN; i++) {
          const float x = S[i * 3 + 0];             // uniform addr -> scalar loads
          const float y = S[i * 3 + 1];
          const float z = S[i * 3 + 2];
          const float dx = qx - x, dy = qy - y, dz = qz - z;
          const float d = dx * dx + dy * dy + dz * dz;
          if (d <= rep_thr && cnt < REP_NS) {
            if (cnt == 0) d0 = d;
            ins5(d, t0, t1, t2, t3, t4);
            cnt++;
          }
        }

        s_t5[w][lane][0] = t0; s_t5[w][lane][1] = t1; s_t5[w][lane][2] = t2;
        s_t5[w][lane][3] = t3; s_t5[w][lane][4] = t4;
        s_d0[w][lane] = d0;
        s_cnt[w][lane] = cnt;
        __syncthreads();

        if (w == 0) {
          int total = 0;
          float fd0 = 0.0f;
          int first_seen = 0;
          float n0 = FLT_MAX, n1 = FLT_MAX, n2 = FLT_MAX, n3 = FLT_MAX, n4 = FLT_MAX;
#pragma unroll
          for (int sg = 0; sg < REP_SEG; sg++) {
            const int c = s_cnt[sg][lane];
            if (c > 0 && !first_seen) { fd0 = s_d0[sg][lane]; first_seen = 1; }
            total += c;
#pragma unroll
            for (int j = 0; j < 5; j++) ins5(s_t5[sg][lane][j], n0, n1, n2, n3, n4);
          }

          if (total > REP_NS) {
            // cap binds across segments (astronomically rare): exact rescan
            int c2 = 0;
            n0 = FLT_MAX; n1 = FLT_MAX; n2 = FLT_MAX; n3 = FLT_MAX; n4 = FLT_MAX;
            for (int i = 0; i < NPTS && c2 < REP_NS; i++) {
              const float dx = qx - P[i * 3 + 0];
              const float dy = qy - P[i * 3 + 1];
              const float dz = qz - P[i * 3 + 2];
              const float d = dx * dx + dy * dy + dz * dz;
              if (d <= rep_thr) { ins5(d, n0, n1, n2, n3, n4); c2++; }
            }
          } else {
            for (int c = total; c < REP_NS; c++) ins5(fd0, n0, n1, n2, n3, n4);
          }

          float sum = rep_term(n1) + rep_term(n2) + rep_term(n3) + rep_term(n4);
#pragma unroll
          for (int off = 32; off >= 1; off >>= 1) sum += __shfl_down(sum, off);
          if (lane == 0) rep_part[t] = (double)sum;
        }
      } else {
        // ---------------- uniform task (8 waves) --------
        const int ball = t - REP_TASKS;
        const int b = ball / NPOINT;
        const float* P = pcd + b * NPTS * 3;

        if (tid == 0) {
          int v = __hip_atomic_load(&fps_idx[ball], __ATOMIC_RELAXED,
                                    __HIP_MEMORY_SCOPE_AGENT);
          while (v < 0) {
            __builtin_amdgcn_s_sleep(32);
            v = __hip_atomic_load(&fps_idx[ball], __ATOMIC_RELAXED,
                                  __HIP_MEMORY_SCOPE_AGENT);
          }
          s_qidx = v;
        }
        __syncthreads();
        const int qidx = s_qidx;
        const float qx = P[qidx * 3 + 0], qy = P[qidx * 3 + 1], qz = P[qidx * 3 + 2];

        // scan this wave's contiguous 1024-point segment (index order kept)
        int wcnt = 0;
        const float* S = P + w * 1024 * 3;
        for (int it = 0; it < 16; it++) {
          const int j = it * 64 + lane;
          const float x = S[j * 3 + 0];
          const float y = S[j * 3 + 1];
          const float z = S[j * 3 + 2];
          const float dx = qx - x, dy = qy - y, dz = qz - z;
          const float d = dx * dx + dy * dy + dz * dz;
          const bool hitp = (d <= up.thr[4]);
          const unsigned long long m = __ballot(hitp);
          if (hitp) {
            const int pos = wcnt + __popcll(m & ((1ull << lane) - 1ull));
            if (pos < UW) {
              wx[w][pos] = x; wy[w][pos] = y; wz[w][pos] = z; wd[w][pos] = d;
            }
          }
          wcnt += __popcll(m);
        }
        if (lane == 0) s_wcnt[w] = min(wcnt, UW);
        __syncthreads();

        int off = 0;
#pragma unroll
        for (int w2 = 0; w2 < 8; w2++) {
          if (w2 == w) break;
          off += s_wcnt[w2];
        }
        for (int i = lane; i < s_wcnt[w]; i += 64) {
          FX[off + i] = wx[w][i]; FY[off + i] = wy[w][i];
          FZ[off + i] = wz[w][i]; FD[off + i] = wd[w][i];
        }
        __syncthreads();
        int c = 0;
#pragma unroll
        for (int w2 = 0; w2 < 8; w2++) c += s_wcnt[w2];   // >=1 (self hit)

        double local = 0.0;
        if (w < 5) {
          const int jp = w;
          const float thr = up.thr[jp];
          const int nsj = up.ns[jp];

          int cnt2 = 0;
          for (int bse = 0; bse < c; bse += 64) {
            const int e = bse + lane;
            const bool pred = (e < c) && (FD[e] <= thr);
            const unsigned long long m = __ballot(pred);
            if (pred) {
              const int pos = cnt2 + __popcll(m & ((1ull << lane) - 1ull));
              if (pos < nsj) {
                CX[jp][pos] = FX[e]; CY[jp][pos] = FY[e]; CZ[jp][pos] = FZ[e];
              }
            }
            cnt2 += __popcll(m);
          }
          const int cj = min(cnt2, nsj);     // >= 1 (self hit)
          const int pads = nsj - cj;
          const int istart = (pads > 0) ? 1 : 0;

          if (pads > 0 && lane == 0) {
            // pad rows + row 0: second-smallest = 0 exactly
            const float ud = sqrtf(fabsf(1e-8f));
            const float dd = ud - up.e[jp];
            const float tt = (dd * dd) / up.eden[jp];
            local += (double)tt * wj_tab[jp] * (double)(pads + 1);
          }

          for (int r = istart + lane; r < cj; r += 64) {
            const float xi = CX[jp][r], yi = CY[jp][r], zi = CZ[jp][r];
            float mm = FLT_MAX;
            for (int e2 = 0; e2 < cj; e2++) {
              if (e2 == r) continue;
              const float dx = xi - CX[jp][e2];
              const float dy = yi - CY[jp][e2];
              const float dz = zi - CZ[jp][e2];
              const float d = dx * dx + dy * dy + dz * dz;
              if (d < mm) mm = d;
            }
            const float ud = sqrtf(fabsf(mm + 1e-8f));
            const float dd = ud - up.e[jp];
            const float tt = (dd * dd) / up.eden[jp];
            local += (double)tt * wj_tab[jp];
          }
        }

#pragma unroll
        for (int o = 32; o >= 1; o >>= 1) local += __shfl_down(local, o);
        if (lane == 0) dpart[w] = local;
        __syncthreads();
        if (tid == 0) {
          double u = 0.0;
#pragma unroll
          for (int w2 = 0; w2 < 8; w2++) u += dpart[w2];
          uni_part[ball] = u;
        }
      }
    }
  }

  // ---------------- arrival + last-block finalize ----------------
  __syncthreads();                   // all block stores issued & drained
  if (tid == 0) {
    __threadfence();                 // release: publish this block's partials
    const int old = __hip_atomic_fetch_add(done, 1, __ATOMIC_ACQ_REL,
                                           __HIP_MEMORY_SCOPE_AGENT);
    s_last = (old == NBLOCKS - 2) ? 1 : 0;   // init -1 -> last sees 254
    if (s_last) __threadfence();     // acquire: see everyone's partials
  }
  __syncthreads();
  if (s_last) {
    double u = 0.0, r = 0.0;
    for (int i = tid; i < NBALLS; i += 512) u += uni_part[i];
    for (int i = tid; i < REP_TASKS; i += 512) r += rep_part[i];
#pragma unroll
    for (int o = 32; o >= 1; o >>= 1) {
      u += __shfl_down(u, o);
      r += __shfl_down(r, o);
    }
    if (lane == 0) { dpart[w] = u; rpart[w] = r; }
    __syncthreads();
    if (tid == 0) {
      double us = 0.0, rs = 0.0;
#pragma unroll
      for (int w2 = 0; w2 < 8; w2++) { us += dpart[w2]; rs += rpart[w2]; }
      out[0] = (float)us;
      out[1] = (float)(rs * (1.0 / 131072.0));
    }
  }
}

// ---------------------------------------------------------------- launch
extern "C" void kernel_launch(void* const* d_in, const int* in_sizes, int n_in,
                              void* d_out, int out_size, void* d_ws, size_t ws_size,
                              hipStream_t stream) {
  (void)in_sizes; (void)n_in; (void)out_size; (void)ws_size;
  const float* pcd = (const float*)d_in[0];
  float* out = (float*)d_out;
  int*    fps      = (int*)((char*)d_ws + WS_FPS_OFF);
  int*    counter  = (int*)((char*)d_ws + WS_CNT_OFF);
  int*    done     = (int*)((char*)d_ws + WS_DONE_OFF);
  double* rep_part = (double*)((char*)d_ws + WS_REP_OFF);
  double* uni_part = (double*)((char*)d_ws + WS_UNI_OFF);

  const float rep_thr = (float)(0.07 * 0.07);

  UniParams up;
  const double ps[5] = {0.004, 0.008, 0.01, 0.012, 0.016};
  for (int j = 0; j < 5; j++) {
    const int ns = (int)(8192.0 * ps[j]);            // 32, 65, 81, 98, 131
    const double r = sqrt(ps[j]);
    up.thr[j] = (float)(r * r);
    const double disk = M_PI * ps[j] / (double)ns;
    const double el = sqrt(2.0 * disk / 1.732);
    up.e[j] = (float)el;
    up.eden[j] = (float)(el + 1e-8);
    up.ns[j] = ns;
  }

  // ONE memset: fps_idx sentinels (0xFF -> negative), task counter -> -1,
  // done counter -> -1.
  hipMemsetAsync(fps, 0xFF, WS_DONE_OFF + sizeof(int), stream);

  static const int kDynLds = NPTS * 3 * (int)sizeof(float);   // 98304
  (void)hipFuncSetAttribute((const void*)fused_kernel,
                            hipFuncAttributeMaxDynamicSharedMemorySize, kDynLds);

  fused_kernel<<<NBLOCKS, 512, kDynLds, stream>>>(pcd, fps, rep_part, uni_part,
                                                  counter, done, out, up, rep_thr);
}

// Round 9
// 395.368 us; speedup vs baseline: 1.1122x; 1.0254x over previous
//
#include <hip/hip_runtime.h>
#include <hip/hip_bf16.h>
#include <cmath>
#include <cfloat>

#define BATCH 4
#define NPTS 8192
#define NPOINT 409
#define NBALLS (BATCH * NPOINT)   // 1636
#define REP_NS 20
#define REP_SEG 8                 // rep segments per query (one per wave)
#define SEG_LEN (NPTS / REP_SEG)  // 1024
#define REP_TASKS 512
#define NTASKS (REP_TASKS + NBALLS)   // 2148
#define NWORKERS 252
#define NBLOCKS (BATCH + NWORKERS)    // 256

#define UW 96                     // uni per-wave hit capacity (E[hits/1024pts]~1.1)
#define UH (8 * UW)               // 768

// ws layout (bytes):
//   [0, 6544)       : fps_idx  int[1636]  (memset 0xFF -> negative sentinel)
//   [6544, 6548)    : task counter       (memset 0xFF -> init -1; t = old+1)
//   [6548, 6552)    : done counter       (memset 0xFF -> init -1)
//   [8192, 12288)   : rep_part double[512]
//   [12288, 25376)  : uni_part double[1636]
// ONE memset covers [0, 6552).
// R9 = R8 + publish reorder: the fps_idx store now issues immediately after
// far is computed, BEFORE the dependent X/Y/Z[far] LDS reads — widening the
// store-ack hiding window (~450 -> ~580 cyc) before the next barrier's
// vmcnt(0) drain. Zero added instructions; same value, same slot, same
// relaxed agent-scope semantics.
#define WS_FPS_OFF 0
#define WS_CNT_OFF 6544
#define WS_DONE_OFF 6548
#define WS_REP_OFF 8192
#define WS_UNI_OFF 12288

typedef float v2f __attribute__((ext_vector_type(2)));

struct UniParams {
  float  thr[5];
  float  e[5];
  float  eden[5];
  int    ns[5];
};

template <int CTRL>
__device__ __forceinline__ unsigned dpp_max_u32(unsigned v) {
  const unsigned o = (unsigned)__builtin_amdgcn_update_dpp(
      0, (int)v, CTRL, 0xf, 0xf, true);
  return o > v ? o : v;
}

__device__ __forceinline__ unsigned long long umax64(unsigned long long a,
                                                     unsigned long long b) {
  return a > b ? a : b;
}

__device__ __forceinline__ void ins5(float v, float& t0, float& t1, float& t2,
                                     float& t3, float& t4) {
  if (v < t4) {
    t4 = v;
    if (t4 < t3) { float tmp = t3; t3 = t4; t4 = tmp; }
    if (t3 < t2) { float tmp = t2; t2 = t3; t3 = tmp; }
    if (t2 < t1) { float tmp = t1; t1 = t2; t2 = tmp; }
    if (t1 < t0) { float tmp = t0; t0 = t1; t1 = tmp; }
  }
}

__device__ __forceinline__ float rep_term(float d) {
  d = fmaxf(d, 0.0f);
  return 0.07f - sqrtf(d) * expf(-(d / 0.0009f));
}

// ---------------------------------------------------------------- fused kernel
// 256 blocks x 512 threads, 1 block/CU (145KB LDS) => ALL blocks co-resident
// by capacity; no dispatch-order assumption.
//   blocks [0,4)   : FPS; publishes fps_idx right after the block argmax
//                    resolves (max store-ack hiding before the next barrier).
//   blocks [4,256) : persistent workers pulling 2148 tasks off an atomic
//                    counter: tasks [0,512) = repulsion, [512,2148) = uniform.
//                    uni tasks poll fps_idx[ball] (0xFF sentinel).
//   all blocks     : arrive on done-counter (init -1 via 0xFF memset); the
//                    LAST block (old == NBLOCKS-2) does the final reduction.
__global__ __launch_bounds__(512, 2) void fused_kernel(const float* __restrict__ pcd,
                                                       int* __restrict__ fps_idx,
                                                       double* __restrict__ rep_part,
                                                       double* __restrict__ uni_part,
                                                       int* __restrict__ counter,
                                                       int* __restrict__ done,
                                                       float* __restrict__ out,
                                                       UniParams up, float rep_thr) {
  const int tid = threadIdx.x;
  const int lane = tid & 63;
  const int w = tid >> 6;
  extern __shared__ float smem[];   // 96 KB: X[8192] Y[8192] Z[8192] (fps only)

  // static shared (distinct storage per phase; no unions -> no cross-task races)
  __shared__ unsigned long long s_key[2][8];
  __shared__ float s_t5[REP_SEG][64][5];
  __shared__ float s_d0[REP_SEG][64];
  __shared__ int   s_cnt[REP_SEG][64];
  __shared__ float wx[8][UW], wy[8][UW], wz[8][UW], wd[8][UW];
  __shared__ int   s_wcnt[8];
  __shared__ float FX[UH], FY[UH], FZ[UH], FD[UH];
  __shared__ float CX[5][131], CY[5][131], CZ[5][131];
  __shared__ double dpart[8], rpart[8];
  __shared__ int s_task, s_qidx, s_last;

  if (blockIdx.x < BATCH) {
    // ---------------- FPS ----------------
    const int b = blockIdx.x;
    const float* P = pcd + b * NPTS * 3;
    float* X = smem;
    float* Y = smem + NPTS;
    float* Z = smem + 2 * NPTS;

    if (tid == 0) {
      // pick 0 is index 0 — publish immediately (unlocks ball 0)
      __hip_atomic_store(&fps_idx[b * NPOINT + 0], 0,
                         __ATOMIC_RELAXED, __HIP_MEMORY_SCOPE_AGENT);
    }

    for (int i = tid; i < NPTS; i += 512) {
      X[i] = P[i * 3 + 0];
      Y[i] = P[i * 3 + 1];
      Z[i] = P[i * 3 + 2];
    }

    v2f px[8], py[8], pz[8], dist[8];
    const int base = tid * 16;
#pragma unroll
    for (int k = 0; k < 8; k++) {
      const int i0 = (base + 2 * k) * 3;
      const int i1 = (base + 2 * k + 1) * 3;
      px[k] = (v2f){P[i0 + 0], P[i1 + 0]};
      py[k] = (v2f){P[i0 + 1], P[i1 + 1]};
      pz[k] = (v2f){P[i0 + 2], P[i1 + 2]};
      dist[k] = (v2f){1e10f, 1e10f};
    }
#pragma unroll
    for (int k = 0; k < 8; k++) {
      asm volatile("" : "+v"(px[k]), "+v"(py[k]), "+v"(pz[k]));
    }

    __syncthreads();

    float fx = X[0], fy = Y[0], fz = Z[0];
    for (int s = 0; s < NPOINT - 1; s++) {    // computes picks 1..408
      const v2f fxv = (v2f){fx, fx};
      const v2f fyv = (v2f){fy, fy};
      const v2f fzv = (v2f){fz, fz};
#pragma unroll
      for (int k = 0; k < 8; k++) {
#pragma clang fp contract(fast)
        const v2f dx = px[k] - fxv;
        const v2f dy = py[k] - fyv;
        const v2f dz = pz[k] - fzv;
        const v2f d  = (dx * dx + dy * dy) + dz * dz;
        dist[k].x = fminf(dist[k].x, d.x);
        dist[k].y = fminf(dist[k].y, d.y);
      }

      // thread-local max, 3-ary grouping -> v_max3_f32 fusion (8 inst vs 15).
      // max over finite floats is association-free -> bit-identical result.
      const float a0 = fmaxf(fmaxf(dist[0].x, dist[0].y), dist[1].x);
      const float a1 = fmaxf(fmaxf(dist[1].y, dist[2].x), dist[2].y);
      const float a2 = fmaxf(fmaxf(dist[3].x, dist[3].y), dist[4].x);
      const float a3 = fmaxf(fmaxf(dist[4].y, dist[5].x), dist[5].y);
      const float a4 = fmaxf(fmaxf(dist[6].x, dist[6].y), dist[7].x);
      const float b0 = fmaxf(fmaxf(a0, a1), a2);
      const float b1 = fmaxf(fmaxf(a3, a4), dist[7].y);
      const float tmax = fmaxf(b0, b1);

      // dist >= 0 -> IEEE f32 bits are order-isomorphic -> u32 DPP max
      const unsigned tb = __float_as_uint(tmax);
      unsigned rb = tb;
      rb = dpp_max_u32<0x111>(rb);   // row_shr:1
      rb = dpp_max_u32<0x112>(rb);   // row_shr:2
      rb = dpp_max_u32<0x114>(rb);   // row_shr:4
      rb = dpp_max_u32<0x118>(rb);   // row_shr:8
      rb = dpp_max_u32<0x142>(rb);   // row_bcast:15
      rb = dpp_max_u32<0x143>(rb);   // row_bcast:31
      const unsigned wb = (unsigned)__builtin_amdgcn_readlane((int)rb, 63);

      const unsigned long long hit = __ballot(tb == wb);
      const int par = s & 1;
      if (tb == wb && (hit & ((1ull << lane) - 1ull)) == 0ull) {
        // first (lowest-lane) holder of the wave max: find smallest local idx
        const float wv = __uint_as_float(wb);
        int li = 0;
#pragma unroll
        for (int j = 15; j >= 0; j--) {
          const float v = (j & 1) ? dist[j >> 1].y : dist[j >> 1].x;
          li = (v == wv) ? j : li;       // descending overwrite -> smallest j
        }
        const unsigned bidx = (unsigned)(base + li);
        s_key[par][w] = ((unsigned long long)wb << 32) |
                        (unsigned long long)(0xFFFFFFFFu - bidx);
      }
      __syncthreads();

      // depth-3 max tree (keys unique: idx distinct -> order-independent)
      const unsigned long long k0 = s_key[par][0], k1 = s_key[par][1];
      const unsigned long long k2 = s_key[par][2], k3 = s_key[par][3];
      const unsigned long long k4 = s_key[par][4], k5 = s_key[par][5];
      const unsigned long long k6 = s_key[par][6], k7 = s_key[par][7];
      const unsigned long long kbk =
          umax64(umax64(umax64(k0, k1), umax64(k2, k3)),
                 umax64(umax64(k4, k5), umax64(k6, k7)));
      const int far = (int)(0xFFFFFFFFu - (unsigned)(kbk & 0xFFFFFFFFull));

      // publish BEFORE the dependent X/Y/Z reads: store issues ~130cyc
      // earlier, widening the ack-hiding window to the next barrier.
      if (tid == 0) {
        __hip_atomic_store(&fps_idx[b * NPOINT + s + 1], far,
                           __ATOMIC_RELAXED, __HIP_MEMORY_SCOPE_AGENT);
      }

      fx = X[far];                   // wave-uniform LDS broadcast (conflict-free)
      fy = Y[far];
      fz = Z[far];
    }
  } else {
    // ---------------- persistent workers (dynamic stealing) ----------------
    const double wj_tab[5] = {0.16 / (5.0 * 1636.0 * 32.0),
                              0.64 / (5.0 * 1636.0 * 65.0),
                              1.0  / (5.0 * 1636.0 * 81.0),
                              1.44 / (5.0 * 1636.0 * 98.0),
                              2.56 / (5.0 * 1636.0 * 131.0)};

    while (true) {
      __syncthreads();               // protects s_task + task-shared reuse
      if (tid == 0) s_task = atomicAdd(counter, 1) + 1;   // counter init -1
      __syncthreads();
      const int t = s_task;
      if (t >= NTASKS) break;        // uniform exit -> arrival

      if (t < REP_TASKS) {
        // ---------------- repulsion task (512 thr) ----------------
        const int b = t >> 7;                       // 128 tasks per batch
        const int q = ((t & 127) << 6) + lane;
        const float* P = pcd + b * NPTS * 3;

        const float qx = P[q * 3 + 0], qy = P[q * 3 + 1], qz = P[q * 3 + 2];

        int cnt = 0;
        float d0 = 0.0f;
        float t0 = FLT_MAX, t1 = FLT_MAX, t2 = FLT_MAX, t3 = FLT_MAX, t4 = FLT_MAX;

        const int wu = __builtin_amdgcn_readfirstlane(w);
        const float* S = P + wu * SEG_LEN * 3;
#pragma unroll 4
        for (int i = 0; i < SEG_LEN; i++) {
          const float x = S[i * 3 + 0];             // uniform addr -> scalar loads
          const float y = S[i * 3 + 1];
          const float z = S[i * 3 + 2];
          const float dx = qx - x, dy = qy - y, dz = qz - z;
          const float d = dx * dx + dy * dy + dz * dz;
          if (d <= rep_thr && cnt < REP_NS) {
            if (cnt == 0) d0 = d;
            ins5(d, t0, t1, t2, t3, t4);
            cnt++;
          }
        }

        s_t5[w][lane][0] = t0; s_t5[w][lane][1] = t1; s_t5[w][lane][2] = t2;
        s_t5[w][lane][3] = t3; s_t5[w][lane][4] = t4;
        s_d0[w][lane] = d0;
        s_cnt[w][lane] = cnt;
        __syncthreads();

        if (w == 0) {
          int total = 0;
          float fd0 = 0.0f;
          int first_seen = 0;
          float n0 = FLT_MAX, n1 = FLT_MAX, n2 = FLT_MAX, n3 = FLT_MAX, n4 = FLT_MAX;
#pragma unroll
          for (int sg = 0; sg < REP_SEG; sg++) {
            const int c = s_cnt[sg][lane];
            if (c > 0 && !first_seen) { fd0 = s_d0[sg][lane]; first_seen = 1; }
            total += c;
#pragma unroll
            for (int j = 0; j < 5; j++) ins5(s_t5[sg][lane][j], n0, n1, n2, n3, n4);
          }

          if (total > REP_NS) {
            // cap binds across segments (astronomically rare): exact rescan
            int c2 = 0;
            n0 = FLT_MAX; n1 = FLT_MAX; n2 = FLT_MAX; n3 = FLT_MAX; n4 = FLT_MAX;
            for (int i = 0; i < NPTS && c2 < REP_NS; i++) {
              const float dx = qx - P[i * 3 + 0];
              const float dy = qy - P[i * 3 + 1];
              const float dz = qz - P[i * 3 + 2];
              const float d = dx * dx + dy * dy + dz * dz;
              if (d <= rep_thr) { ins5(d, n0, n1, n2, n3, n4); c2++; }
            }
          } else {
            for (int c = total; c < REP_NS; c++) ins5(fd0, n0, n1, n2, n3, n4);
          }

          float sum = rep_term(n1) + rep_term(n2) + rep_term(n3) + rep_term(n4);
#pragma unroll
          for (int off = 32; off >= 1; off >>= 1) sum += __shfl_down(sum, off);
          if (lane == 0) rep_part[t] = (double)sum;
        }
      } else {
        // ---------------- uniform task (8 waves) --------
        const int ball = t - REP_TASKS;
        const int b = ball / NPOINT;
        const float* P = pcd + b * NPTS * 3;

        if (tid == 0) {
          int v = __hip_atomic_load(&fps_idx[ball], __ATOMIC_RELAXED,
                                    __HIP_MEMORY_SCOPE_AGENT);
          while (v < 0) {
            __builtin_amdgcn_s_sleep(32);
            v = __hip_atomic_load(&fps_idx[ball], __ATOMIC_RELAXED,
                                  __HIP_MEMORY_SCOPE_AGENT);
          }
          s_qidx = v;
        }
        __syncthreads();
        const int qidx = s_qidx;
        const float qx = P[qidx * 3 + 0], qy = P[qidx * 3 + 1], qz = P[qidx * 3 + 2];

        // scan this wave's contiguous 1024-point segment (index order kept)
        int wcnt = 0;
        const float* S = P + w * 1024 * 3;
        for (int it = 0; it < 16; it++) {
          const int j = it * 64 + lane;
          const float x = S[j * 3 + 0];
          const float y = S[j * 3 + 1];
          const float z = S[j * 3 + 2];
          const float dx = qx - x, dy = qy - y, dz = qz - z;
          const float d = dx * dx + dy * dy + dz * dz;
          const bool hitp = (d <= up.thr[4]);
          const unsigned long long m = __ballot(hitp);
          if (hitp) {
            const int pos = wcnt + __popcll(m & ((1ull << lane) - 1ull));
            if (pos < UW) {
              wx[w][pos] = x; wy[w][pos] = y; wz[w][pos] = z; wd[w][pos] = d;
            }
          }
          wcnt += __popcll(m);
        }
        if (lane == 0) s_wcnt[w] = min(wcnt, UW);
        __syncthreads();

        int off = 0;
#pragma unroll
        for (int w2 = 0; w2 < 8; w2++) {
          if (w2 == w) break;
          off += s_wcnt[w2];
        }
        for (int i = lane; i < s_wcnt[w]; i += 64) {
          FX[off + i] = wx[w][i]; FY[off + i] = wy[w][i];
          FZ[off + i] = wz[w][i]; FD[off + i] = wd[w][i];
        }
        __syncthreads();
        int c = 0;
#pragma unroll
        for (int w2 = 0; w2 < 8; w2++) c += s_wcnt[w2];   // >=1 (self hit)

        double local = 0.0;
        if (w < 5) {
          const int jp = w;
          const float thr = up.thr[jp];
          const int nsj = up.ns[jp];

          int cnt2 = 0;
          for (int bse = 0; bse < c; bse += 64) {
            const int e = bse + lane;
            const bool pred = (e < c) && (FD[e] <= thr);
            const unsigned long long m = __ballot(pred);
            if (pred) {
              const int pos = cnt2 + __popcll(m & ((1ull << lane) - 1ull));
              if (pos < nsj) {
                CX[jp][pos] = FX[e]; CY[jp][pos] = FY[e]; CZ[jp][pos] = FZ[e];
              }
            }
            cnt2 += __popcll(m);
          }
          const int cj = min(cnt2, nsj);     // >= 1 (self hit)
          const int pads = nsj - cj;
          const int istart = (pads > 0) ? 1 : 0;

          if (pads > 0 && lane == 0) {
            // pad rows + row 0: second-smallest = 0 exactly
            const float ud = sqrtf(fabsf(1e-8f));
            const float dd = ud - up.e[jp];
            const float tt = (dd * dd) / up.eden[jp];
            local += (double)tt * wj_tab[jp] * (double)(pads + 1);
          }

          for (int r = istart + lane; r < cj; r += 64) {
            const float xi = CX[jp][r], yi = CY[jp][r], zi = CZ[jp][r];
            float mm = FLT_MAX;
            for (int e2 = 0; e2 < cj; e2++) {
              if (e2 == r) continue;
              const float dx = xi - CX[jp][e2];
              const float dy = yi - CY[jp][e2];
              const float dz = zi - CZ[jp][e2];
              const float d = dx * dx + dy * dy + dz * dz;
              if (d < mm) mm = d;
            }
            const float ud = sqrtf(fabsf(mm + 1e-8f));
            const float dd = ud - up.e[jp];
            const float tt = (dd * dd) / up.eden[jp];
            local += (double)tt * wj_tab[jp];
          }
        }

#pragma unroll
        for (int o = 32; o >= 1; o >>= 1) local += __shfl_down(local, o);
        if (lane == 0) dpart[w] = local;
        __syncthreads();
        if (tid == 0) {
          double u = 0.0;
#pragma unroll
          for (int w2 = 0; w2 < 8; w2++) u += dpart[w2];
          uni_part[ball] = u;
        }
      }
    }
  }

  // ---------------- arrival + last-block finalize ----------------
  __syncthreads();                   // all block stores issued & drained
  if (tid == 0) {
    __threadfence();                 // release: publish this block's partials
    const int old = __hip_atomic_fetch_add(done, 1, __ATOMIC_ACQ_REL,
                                           __HIP_MEMORY_SCOPE_AGENT);
    s_last = (old == NBLOCKS - 2) ? 1 : 0;   // init -1 -> last sees 254
    if (s_last) __threadfence();     // acquire: see everyone's partials
  }
  __syncthreads();
  if (s_last) {
    double u = 0.0, r = 0.0;
    for (int i = tid; i < NBALLS; i += 512) u += uni_part[i];
    for (int i = tid; i < REP_TASKS; i += 512) r += rep_part[i];
#pragma unroll
    for (int o = 32; o >= 1; o >>= 1) {
      u += __shfl_down(u, o);
      r += __shfl_down(r, o);
    }
    if (lane == 0) { dpart[w] = u; rpart[w] = r; }
    __syncthreads();
    if (tid == 0) {
      double us = 0.0, rs = 0.0;
#pragma unroll
      for (int w2 = 0; w2 < 8; w2++) { us += dpart[w2]; rs += rpart[w2]; }
      out[0] = (float)us;
      out[1] = (float)(rs * (1.0 / 131072.0));
    }
  }
}

// ---------------------------------------------------------------- launch
extern "C" void kernel_launch(void* const* d_in, const int* in_sizes, int n_in,
                              void* d_out, int out_size, void* d_ws, size_t ws_size,
                              hipStream_t stream) {
  (void)in_sizes; (void)n_in; (void)out_size; (void)ws_size;
  const float* pcd = (const float*)d_in[0];
  float* out = (float*)d_out;
  int*    fps      = (int*)((char*)d_ws + WS_FPS_OFF);
  int*    counter  = (int*)((char*)d_ws + WS_CNT_OFF);
  int*    done     = (int*)((char*)d_ws + WS_DONE_OFF);
  double* rep_part = (double*)((char*)d_ws + WS_REP_OFF);
  double* uni_part = (double*)((char*)d_ws + WS_UNI_OFF);

  const float rep_thr = (float)(0.07 * 0.07);

  UniParams up;
  const double ps[5] = {0.004, 0.008, 0.01, 0.012, 0.016};
  for (int j = 0; j < 5; j++) {
    const int ns = (int)(8192.0 * ps[j]);            // 32, 65, 81, 98, 131
    const double r = sqrt(ps[j]);
    up.thr[j] = (float)(r * r);
    const double disk = M_PI * ps[j] / (double)ns;
    const double el = sqrt(2.0 * disk / 1.732);
    up.e[j] = (float)el;
    up.eden[j] = (float)(el + 1e-8);
    up.ns[j] = ns;
  }

  // ONE memset: fps_idx sentinels (0xFF -> negative), task counter -> -1,
  // done counter -> -1.
  hipMemsetAsync(fps, 0xFF, WS_DONE_OFF + sizeof(int), stream);

  static const int kDynLds = NPTS * 3 * (int)sizeof(float);   // 98304
  (void)hipFuncSetAttribute((const void*)fused_kernel,
                            hipFuncAttributeMaxDynamicSharedMemorySize, kDynLds);

  fused_kernel<<<NBLOCKS, 512, kDynLds, stream>>>(pcd, fps, rep_part, uni_part,
                                                  counter, done, out, up, rep_thr);
}

// Round 10
// 393.800 us; speedup vs baseline: 1.1167x; 1.0040x over previous
//
#include <hip/hip_runtime.h>
#include <hip/hip_bf16.h>
#include <cmath>
#include <cfloat>

#define BATCH 4
#define NPTS 8192
#define NPOINT 409
#define NBALLS (BATCH * NPOINT)   // 1636
#define REP_NS 20
#define REP_SEG 8                 // rep segments per query (one per wave)
#define SEG_LEN (NPTS / REP_SEG)  // 1024
#define REP_TASKS 512
#define NTASKS (REP_TASKS + NBALLS)   // 2148
#define NWORKERS 252
#define NBLOCKS (BATCH + NWORKERS)    // 256

#define UW 96                     // uni per-wave hit capacity (E[hits/1024pts]~1.1)
#define UH (8 * UW)               // 768

// ws layout (bytes):
//   [0, 6544)       : fps_idx  int[1636]  (memset 0xFF -> negative sentinel)
//   [6544, 6548)    : task counter       (memset 0xFF -> init -1; t = old+1)
//   [6548, 6552)    : done counter       (memset 0xFF -> init -1)
//   [8192, 12288)   : rep_part double[512]
//   [12288, 25376)  : uni_part double[1636]
// ONE memset covers [0, 6552).
// R10 = R9 + lgkm-only barrier in the FPS loop: __syncthreads() drains
// vmcnt(0), forcing the publishing wave to eat the agent-scope store ack
// every step (R9 proved this exposure: publish reorder alone was -16us).
// The publish has NO intra-block reader — only LDS (s_key) needs barrier
// ordering — so `s_waitcnt lgkmcnt(0); s_barrier` is sufficient and lets
// the store stay in flight across steps. Final __threadfence drains all.
#define WS_FPS_OFF 0
#define WS_CNT_OFF 6544
#define WS_DONE_OFF 6548
#define WS_REP_OFF 8192
#define WS_UNI_OFF 12288

typedef float v2f __attribute__((ext_vector_type(2)));

struct UniParams {
  float  thr[5];
  float  e[5];
  float  eden[5];
  int    ns[5];
};

template <int CTRL>
__device__ __forceinline__ unsigned dpp_max_u32(unsigned v) {
  const unsigned o = (unsigned)__builtin_amdgcn_update_dpp(
      0, (int)v, CTRL, 0xf, 0xf, true);
  return o > v ? o : v;
}

__device__ __forceinline__ unsigned long long umax64(unsigned long long a,
                                                     unsigned long long b) {
  return a > b ? a : b;
}

__device__ __forceinline__ void ins5(float v, float& t0, float& t1, float& t2,
                                     float& t3, float& t4) {
  if (v < t4) {
    t4 = v;
    if (t4 < t3) { float tmp = t3; t3 = t4; t4 = tmp; }
    if (t3 < t2) { float tmp = t2; t2 = t3; t3 = tmp; }
    if (t2 < t1) { float tmp = t1; t1 = t2; t2 = tmp; }
    if (t1 < t0) { float tmp = t0; t0 = t1; t1 = tmp; }
  }
}

__device__ __forceinline__ float rep_term(float d) {
  d = fmaxf(d, 0.0f);
  return 0.07f - sqrtf(d) * expf(-(d / 0.0009f));
}

// ---------------------------------------------------------------- fused kernel
// 256 blocks x 512 threads, 1 block/CU (145KB LDS) => ALL blocks co-resident
// by capacity; no dispatch-order assumption.
//   blocks [0,4)   : FPS; publishes fps_idx right after the block argmax
//                    resolves; FPS-loop barrier waits lgkmcnt only (LDS),
//                    letting the publish store ride across steps.
//   blocks [4,256) : persistent workers pulling 2148 tasks off an atomic
//                    counter: tasks [0,512) = repulsion, [512,2148) = uniform.
//                    uni tasks poll fps_idx[ball] (0xFF sentinel).
//   all blocks     : arrive on done-counter (init -1 via 0xFF memset); the
//                    LAST block (old == NBLOCKS-2) does the final reduction.
__global__ __launch_bounds__(512, 2) void fused_kernel(const float* __restrict__ pcd,
                                                       int* __restrict__ fps_idx,
                                                       double* __restrict__ rep_part,
                                                       double* __restrict__ uni_part,
                                                       int* __restrict__ counter,
                                                       int* __restrict__ done,
                                                       float* __restrict__ out,
                                                       UniParams up, float rep_thr) {
  const int tid = threadIdx.x;
  const int lane = tid & 63;
  const int w = tid >> 6;
  extern __shared__ float smem[];   // 96 KB: X[8192] Y[8192] Z[8192] (fps only)

  // static shared (distinct storage per phase; no unions -> no cross-task races)
  __shared__ unsigned long long s_key[2][8];
  __shared__ float s_t5[REP_SEG][64][5];
  __shared__ float s_d0[REP_SEG][64];
  __shared__ int   s_cnt[REP_SEG][64];
  __shared__ float wx[8][UW], wy[8][UW], wz[8][UW], wd[8][UW];
  __shared__ int   s_wcnt[8];
  __shared__ float FX[UH], FY[UH], FZ[UH], FD[UH];
  __shared__ float CX[5][131], CY[5][131], CZ[5][131];
  __shared__ double dpart[8], rpart[8];
  __shared__ int s_task, s_qidx, s_last;

  if (blockIdx.x < BATCH) {
    // ---------------- FPS ----------------
    const int b = blockIdx.x;
    const float* P = pcd + b * NPTS * 3;
    float* X = smem;
    float* Y = smem + NPTS;
    float* Z = smem + 2 * NPTS;

    if (tid == 0) {
      // pick 0 is index 0 — publish immediately (unlocks ball 0)
      __hip_atomic_store(&fps_idx[b * NPOINT + 0], 0,
                         __ATOMIC_RELAXED, __HIP_MEMORY_SCOPE_AGENT);
    }

    for (int i = tid; i < NPTS; i += 512) {
      X[i] = P[i * 3 + 0];
      Y[i] = P[i * 3 + 1];
      Z[i] = P[i * 3 + 2];
    }

    v2f px[8], py[8], pz[8], dist[8];
    const int base = tid * 16;
#pragma unroll
    for (int k = 0; k < 8; k++) {
      const int i0 = (base + 2 * k) * 3;
      const int i1 = (base + 2 * k + 1) * 3;
      px[k] = (v2f){P[i0 + 0], P[i1 + 0]};
      py[k] = (v2f){P[i0 + 1], P[i1 + 1]};
      pz[k] = (v2f){P[i0 + 2], P[i1 + 2]};
      dist[k] = (v2f){1e10f, 1e10f};
    }
#pragma unroll
    for (int k = 0; k < 8; k++) {
      asm volatile("" : "+v"(px[k]), "+v"(py[k]), "+v"(pz[k]));
    }

    __syncthreads();

    float fx = X[0], fy = Y[0], fz = Z[0];
    for (int s = 0; s < NPOINT - 1; s++) {    // computes picks 1..408
      const v2f fxv = (v2f){fx, fx};
      const v2f fyv = (v2f){fy, fy};
      const v2f fzv = (v2f){fz, fz};
#pragma unroll
      for (int k = 0; k < 8; k++) {
#pragma clang fp contract(fast)
        const v2f dx = px[k] - fxv;
        const v2f dy = py[k] - fyv;
        const v2f dz = pz[k] - fzv;
        const v2f d  = (dx * dx + dy * dy) + dz * dz;
        dist[k].x = fminf(dist[k].x, d.x);
        dist[k].y = fminf(dist[k].y, d.y);
      }

      // thread-local max, 3-ary grouping -> v_max3_f32 fusion (8 inst vs 15).
      // max over finite floats is association-free -> bit-identical result.
      const float a0 = fmaxf(fmaxf(dist[0].x, dist[0].y), dist[1].x);
      const float a1 = fmaxf(fmaxf(dist[1].y, dist[2].x), dist[2].y);
      const float a2 = fmaxf(fmaxf(dist[3].x, dist[3].y), dist[4].x);
      const float a3 = fmaxf(fmaxf(dist[4].y, dist[5].x), dist[5].y);
      const float a4 = fmaxf(fmaxf(dist[6].x, dist[6].y), dist[7].x);
      const float b0 = fmaxf(fmaxf(a0, a1), a2);
      const float b1 = fmaxf(fmaxf(a3, a4), dist[7].y);
      const float tmax = fmaxf(b0, b1);

      // dist >= 0 -> IEEE f32 bits are order-isomorphic -> u32 DPP max
      const unsigned tb = __float_as_uint(tmax);
      unsigned rb = tb;
      rb = dpp_max_u32<0x111>(rb);   // row_shr:1
      rb = dpp_max_u32<0x112>(rb);   // row_shr:2
      rb = dpp_max_u32<0x114>(rb);   // row_shr:4
      rb = dpp_max_u32<0x118>(rb);   // row_shr:8
      rb = dpp_max_u32<0x142>(rb);   // row_bcast:15
      rb = dpp_max_u32<0x143>(rb);   // row_bcast:31
      const unsigned wb = (unsigned)__builtin_amdgcn_readlane((int)rb, 63);

      const unsigned long long hit = __ballot(tb == wb);
      const int par = s & 1;
      if (tb == wb && (hit & ((1ull << lane) - 1ull)) == 0ull) {
        // first (lowest-lane) holder of the wave max: find smallest local idx
        const float wv = __uint_as_float(wb);
        int li = 0;
#pragma unroll
        for (int j = 15; j >= 0; j--) {
          const float v = (j & 1) ? dist[j >> 1].y : dist[j >> 1].x;
          li = (v == wv) ? j : li;       // descending overwrite -> smallest j
        }
        const unsigned bidx = (unsigned)(base + li);
        s_key[par][w] = ((unsigned long long)wb << 32) |
                        (unsigned long long)(0xFFFFFFFFu - bidx);
      }

      // lgkm-only barrier: order LDS (s_key) across waves WITHOUT draining
      // the in-flight fps_idx publish store (no intra-block reader exists).
      asm volatile("s_waitcnt lgkmcnt(0)\n\ts_barrier" ::: "memory");

      // depth-3 max tree (keys unique: idx distinct -> order-independent)
      const unsigned long long k0 = s_key[par][0], k1 = s_key[par][1];
      const unsigned long long k2 = s_key[par][2], k3 = s_key[par][3];
      const unsigned long long k4 = s_key[par][4], k5 = s_key[par][5];
      const unsigned long long k6 = s_key[par][6], k7 = s_key[par][7];
      const unsigned long long kbk =
          umax64(umax64(umax64(k0, k1), umax64(k2, k3)),
                 umax64(umax64(k4, k5), umax64(k6, k7)));
      const int far = (int)(0xFFFFFFFFu - (unsigned)(kbk & 0xFFFFFFFFull));

      // publish BEFORE the dependent X/Y/Z reads (R9: -16us)
      if (tid == 0) {
        __hip_atomic_store(&fps_idx[b * NPOINT + s + 1], far,
                           __ATOMIC_RELAXED, __HIP_MEMORY_SCOPE_AGENT);
      }

      fx = X[far];                   // wave-uniform LDS broadcast (conflict-free)
      fy = Y[far];
      fz = Z[far];
    }
  } else {
    // ---------------- persistent workers (dynamic stealing) ----------------
    const double wj_tab[5] = {0.16 / (5.0 * 1636.0 * 32.0),
                              0.64 / (5.0 * 1636.0 * 65.0),
                              1.0  / (5.0 * 1636.0 * 81.0),
                              1.44 / (5.0 * 1636.0 * 98.0),
                              2.56 / (5.0 * 1636.0 * 131.0)};

    while (true) {
      __syncthreads();               // protects s_task + task-shared reuse
      if (tid == 0) s_task = atomicAdd(counter, 1) + 1;   // counter init -1
      __syncthreads();
      const int t = s_task;
      if (t >= NTASKS) break;        // uniform exit -> arrival

      if (t < REP_TASKS) {
        // ---------------- repulsion task (512 thr) ----------------
        const int b = t >> 7;                       // 128 tasks per batch
        const int q = ((t & 127) << 6) + lane;
        const float* P = pcd + b * NPTS * 3;

        const float qx = P[q * 3 + 0], qy = P[q * 3 + 1], qz = P[q * 3 + 2];

        int cnt = 0;
        float d0 = 0.0f;
        float t0 = FLT_MAX, t1 = FLT_MAX, t2 = FLT_MAX, t3 = FLT_MAX, t4 = FLT_MAX;

        const int wu = __builtin_amdgcn_readfirstlane(w);
        const float* S = P + wu * SEG_LEN * 3;
#pragma unroll 4
        for (int i = 0; i < SEG_LEN; i++) {
          const float x = S[i * 3 + 0];             // uniform addr -> scalar loads
          const float y = S[i * 3 + 1];
          const float z = S[i * 3 + 2];
          const float dx = qx - x, dy = qy - y, dz = qz - z;
          const float d = dx * dx + dy * dy + dz * dz;
          if (d <= rep_thr && cnt < REP_NS) {
            if (cnt == 0) d0 = d;
            ins5(d, t0, t1, t2, t3, t4);
            cnt++;
          }
        }

        s_t5[w][lane][0] = t0; s_t5[w][lane][1] = t1; s_t5[w][lane][2] = t2;
        s_t5[w][lane][3] = t3; s_t5[w][lane][4] = t4;
        s_d0[w][lane] = d0;
        s_cnt[w][lane] = cnt;
        __syncthreads();

        if (w == 0) {
          int total = 0;
          float fd0 = 0.0f;
          int first_seen = 0;
          float n0 = FLT_MAX, n1 = FLT_MAX, n2 = FLT_MAX, n3 = FLT_MAX, n4 = FLT_MAX;
#pragma unroll
          for (int sg = 0; sg < REP_SEG; sg++) {
            const int c = s_cnt[sg][lane];
            if (c > 0 && !first_seen) { fd0 = s_d0[sg][lane]; first_seen = 1; }
            total += c;
#pragma unroll
            for (int j = 0; j < 5; j++) ins5(s_t5[sg][lane][j], n0, n1, n2, n3, n4);
          }

          if (total > REP_NS) {
            // cap binds across segments (astronomically rare): exact rescan
            int c2 = 0;
            n0 = FLT_MAX; n1 = FLT_MAX; n2 = FLT_MAX; n3 = FLT_MAX; n4 = FLT_MAX;
            for (int i = 0; i < NPTS && c2 < REP_NS; i++) {
              const float dx = qx - P[i * 3 + 0];
              const float dy = qy - P[i * 3 + 1];
              const float dz = qz - P[i * 3 + 2];
              const float d = dx * dx + dy * dy + dz * dz;
              if (d <= rep_thr) { ins5(d, n0, n1, n2, n3, n4); c2++; }
            }
          } else {
            for (int c = total; c < REP_NS; c++) ins5(fd0, n0, n1, n2, n3, n4);
          }

          float sum = rep_term(n1) + rep_term(n2) + rep_term(n3) + rep_term(n4);
#pragma unroll
          for (int off = 32; off >= 1; off >>= 1) sum += __shfl_down(sum, off);
          if (lane == 0) rep_part[t] = (double)sum;
        }
      } else {
        // ---------------- uniform task (8 waves) --------
        const int ball = t - REP_TASKS;
        const int b = ball / NPOINT;
        const float* P = pcd + b * NPTS * 3;

        if (tid == 0) {
          int v = __hip_atomic_load(&fps_idx[ball], __ATOMIC_RELAXED,
                                    __HIP_MEMORY_SCOPE_AGENT);
          while (v < 0) {
            __builtin_amdgcn_s_sleep(32);
            v = __hip_atomic_load(&fps_idx[ball], __ATOMIC_RELAXED,
                                  __HIP_MEMORY_SCOPE_AGENT);
          }
          s_qidx = v;
        }
        __syncthreads();
        const int qidx = s_qidx;
        const float qx = P[qidx * 3 + 0], qy = P[qidx * 3 + 1], qz = P[qidx * 3 + 2];

        // scan this wave's contiguous 1024-point segment (index order kept)
        int wcnt = 0;
        const float* S = P + w * 1024 * 3;
        for (int it = 0; it < 16; it++) {
          const int j = it * 64 + lane;
          const float x = S[j * 3 + 0];
          const float y = S[j * 3 + 1];
          const float z = S[j * 3 + 2];
          const float dx = qx - x, dy = qy - y, dz = qz - z;
          const float d = dx * dx + dy * dy + dz * dz;
          const bool hitp = (d <= up.thr[4]);
          const unsigned long long m = __ballot(hitp);
          if (hitp) {
            const int pos = wcnt + __popcll(m & ((1ull << lane) - 1ull));
            if (pos < UW) {
              wx[w][pos] = x; wy[w][pos] = y; wz[w][pos] = z; wd[w][pos] = d;
            }
          }
          wcnt += __popcll(m);
        }
        if (lane == 0) s_wcnt[w] = min(wcnt, UW);
        __syncthreads();

        int off = 0;
#pragma unroll
        for (int w2 = 0; w2 < 8; w2++) {
          if (w2 == w) break;
          off += s_wcnt[w2];
        }
        for (int i = lane; i < s_wcnt[w]; i += 64) {
          FX[off + i] = wx[w][i]; FY[off + i] = wy[w][i];
          FZ[off + i] = wz[w][i]; FD[off + i] = wd[w][i];
        }
        __syncthreads();
        int c = 0;
#pragma unroll
        for (int w2 = 0; w2 < 8; w2++) c += s_wcnt[w2];   // >=1 (self hit)

        double local = 0.0;
        if (w < 5) {
          const int jp = w;
          const float thr = up.thr[jp];
          const int nsj = up.ns[jp];

          int cnt2 = 0;
          for (int bse = 0; bse < c; bse += 64) {
            const int e = bse + lane;
            const bool pred = (e < c) && (FD[e] <= thr);
            const unsigned long long m = __ballot(pred);
            if (pred) {
              const int pos = cnt2 + __popcll(m & ((1ull << lane) - 1ull));
              if (pos < nsj) {
                CX[jp][pos] = FX[e]; CY[jp][pos] = FY[e]; CZ[jp][pos] = FZ[e];
              }
            }
            cnt2 += __popcll(m);
          }
          const int cj = min(cnt2, nsj);     // >= 1 (self hit)
          const int pads = nsj - cj;
          const int istart = (pads > 0) ? 1 : 0;

          if (pads > 0 && lane == 0) {
            // pad rows + row 0: second-smallest = 0 exactly
            const float ud = sqrtf(fabsf(1e-8f));
            const float dd = ud - up.e[jp];
            const float tt = (dd * dd) / up.eden[jp];
            local += (double)tt * wj_tab[jp] * (double)(pads + 1);
          }

          for (int r = istart + lane; r < cj; r += 64) {
            const float xi = CX[jp][r], yi = CY[jp][r], zi = CZ[jp][r];
            float mm = FLT_MAX;
            for (int e2 = 0; e2 < cj; e2++) {
              if (e2 == r) continue;
              const float dx = xi - CX[jp][e2];
              const float dy = yi - CY[jp][e2];
              const float dz = zi - CZ[jp][e2];
              const float d = dx * dx + dy * dy + dz * dz;
              if (d < mm) mm = d;
            }
            const float ud = sqrtf(fabsf(mm + 1e-8f));
            const float dd = ud - up.e[jp];
            const float tt = (dd * dd) / up.eden[jp];
            local += (double)tt * wj_tab[jp];
          }
        }

#pragma unroll
        for (int o = 32; o >= 1; o >>= 1) local += __shfl_down(local, o);
        if (lane == 0) dpart[w] = local;
        __syncthreads();
        if (tid == 0) {
          double u = 0.0;
#pragma unroll
          for (int w2 = 0; w2 < 8; w2++) u += dpart[w2];
          uni_part[ball] = u;
        }
      }
    }
  }

  // ---------------- arrival + last-block finalize ----------------
  __syncthreads();                   // all block stores issued & drained
  if (tid == 0) {
    __threadfence();                 // release: publish this block's partials
    const int old = __hip_atomic_fetch_add(done, 1, __ATOMIC_ACQ_REL,
                                           __HIP_MEMORY_SCOPE_AGENT);
    s_last = (old == NBLOCKS - 2) ? 1 : 0;   // init -1 -> last sees 254
    if (s_last) __threadfence();     // acquire: see everyone's partials
  }
  __syncthreads();
  if (s_last) {
    double u = 0.0, r = 0.0;
    for (int i = tid; i < NBALLS; i += 512) u += uni_part[i];
    for (int i = tid; i < REP_TASKS; i += 512) r += rep_part[i];
#pragma unroll
    for (int o = 32; o >= 1; o >>= 1) {
      u += __shfl_down(u, o);
      r += __shfl_down(r, o);
    }
    if (lane == 0) { dpart[w] = u; rpart[w] = r; }
    __syncthreads();
    if (tid == 0) {
      double us = 0.0, rs = 0.0;
#pragma unroll
      for (int w2 = 0; w2 < 8; w2++) { us += dpart[w2]; rs += rpart[w2]; }
      out[0] = (float)us;
      out[1] = (float)(rs * (1.0 / 131072.0));
    }
  }
}

// ---------------------------------------------------------------- launch
extern "C" void kernel_launch(void* const* d_in, const int* in_sizes, int n_in,
                              void* d_out, int out_size, void* d_ws, size_t ws_size,
                              hipStream_t stream) {
  (void)in_sizes; (void)n_in; (void)out_size; (void)ws_size;
  const float* pcd = (const float*)d_in[0];
  float* out = (float*)d_out;
  int*    fps      = (int*)((char*)d_ws + WS_FPS_OFF);
  int*    counter  = (int*)((char*)d_ws + WS_CNT_OFF);
  int*    done     = (int*)((char*)d_ws + WS_DONE_OFF);
  double* rep_part = (double*)((char*)d_ws + WS_REP_OFF);
  double* uni_part = (double*)((char*)d_ws + WS_UNI_OFF);

  const float rep_thr = (float)(0.07 * 0.07);

  UniParams up;
  const double ps[5] = {0.004, 0.008, 0.01, 0.012, 0.016};
  for (int j = 0; j < 5; j++) {
    const int ns = (int)(8192.0 * ps[j]);            // 32, 65, 81, 98, 131
    const double r = sqrt(ps[j]);
    up.thr[j] = (float)(r * r);
    const double disk = M_PI * ps[j] / (double)ns;
    const double el = sqrt(2.0 * disk / 1.732);
    up.e[j] = (float)el;
    up.eden[j] = (float)(el + 1e-8);
    up.ns[j] = ns;
  }

  // ONE memset: fps_idx sentinels (0xFF -> negative), task counter -> -1,
  // done counter -> -1.
  hipMemsetAsync(fps, 0xFF, WS_DONE_OFF + sizeof(int), stream);

  static const int kDynLds = NPTS * 3 * (int)sizeof(float);   // 98304
  (void)hipFuncSetAttribute((const void*)fused_kernel,
                            hipFuncAttributeMaxDynamicSharedMemorySize, kDynLds);

  fused_kernel<<<NBLOCKS, 512, kDynLds, stream>>>(pcd, fps, rep_part, uni_part,
                                                  counter, done, out, up, rep_thr);
}